// Round 2
// baseline (36.751 us; speedup 1.0000x reference)
//
#include <hip/hip_runtime.h>
#include <math.h>

#define H 2048
#define NV 32
#define NK 16
#define DK 128
#define DV 128
#define KEY_DIM 2048
#define VALUE_DIM 4096
#define CONV_DIM 8192               // 2*KEY_DIM + VALUE_DIM
#define N_PROJ_ROWS (CONV_DIM + VALUE_DIM + NV + NV)   // 12352

// workspace float offsets
#define WS_CONVOUT 0                 // 8192
#define WS_Z       8192              // 4096
#define WS_B       12288             // 32
#define WS_A       12320             // 32
#define WS_OUTVEC  12352             // 4096

// d_out float offsets
#define OUT_HIDDEN 0                 // 2048
#define OUT_CONV   2048              // 32768
#define OUT_REC    (2048 + 32768)    // 524288

__device__ __forceinline__ float wave_reduce_sum(float v) {
    #pragma unroll
    for (int off = 32; off > 0; off >>= 1)
        v += __shfl_down(v, off, 64);
    return v;
}

__device__ __forceinline__ float silu_f(float x) { return x / (1.f + expf(-x)); }

// ---------------- Kernel 1: fused projections + conv update ----------------
// One wave (64 lanes) per output row. Rows: [0,8192) qkv, [8192,12288) z,
// [12288,12320) b, [12320,12352) a.
__global__ __launch_bounds__(256) void proj_conv_kernel(
    const float* __restrict__ x,          // 2048
    const float* __restrict__ qkv_w,      // 8192x2048
    const float* __restrict__ z_w,        // 4096x2048
    const float* __restrict__ b_w,        // 32x2048
    const float* __restrict__ a_w,        // 32x2048
    const float* __restrict__ conv_state, // 8192x4
    const float* __restrict__ conv_w,     // 8192x4
    float* __restrict__ ws,
    float* __restrict__ d_out)
{
    int row  = blockIdx.x * 4 + (threadIdx.x >> 6);
    int lane = threadIdx.x & 63;
    if (row >= N_PROJ_ROWS) return;

    const float* w;
    if      (row < CONV_DIM)                  w = qkv_w + (size_t)row * H;
    else if (row < CONV_DIM + VALUE_DIM)      w = z_w   + (size_t)(row - CONV_DIM) * H;
    else if (row < CONV_DIM + VALUE_DIM + NV) w = b_w   + (size_t)(row - CONV_DIM - VALUE_DIM) * H;
    else                                      w = a_w   + (size_t)(row - CONV_DIM - VALUE_DIM - NV) * H;

    const float4* w4 = (const float4*)w;
    const float4* x4 = (const float4*)x;
    float acc = 0.f;
    #pragma unroll
    for (int i = 0; i < H / 4 / 64; ++i) {   // 8 iterations, 16B/lane each
        float4 a4 = w4[lane + i * 64];
        float4 b4 = x4[lane + i * 64];
        acc += a4.x * b4.x + a4.y * b4.y + a4.z * b4.z + a4.w * b4.w;
    }
    acc = wave_reduce_sum(acc);

    if (lane == 0) {
        if (row < CONV_DIM) {
            // conv epilogue: win = [cs1, cs2, cs3, mixed_qkv]
            float c1 = conv_state[row * 4 + 1];
            float c2 = conv_state[row * 4 + 2];
            float c3 = conv_state[row * 4 + 3];
            float w0 = conv_w[row * 4 + 0];
            float w1 = conv_w[row * 4 + 1];
            float w2 = conv_w[row * 4 + 2];
            float w3 = conv_w[row * 4 + 3];
            float s = c1 * w0 + c2 * w1 + c3 * w2 + acc * w3;
            ws[WS_CONVOUT + row] = silu_f(s);
            *(float4*)(d_out + OUT_CONV + row * 4) = make_float4(c1, c2, c3, acc);
        } else if (row < CONV_DIM + VALUE_DIM) {
            ws[WS_Z + (row - CONV_DIM)] = acc;               // raw z (silu applied later)
        } else if (row < CONV_DIM + VALUE_DIM + NV) {
            ws[WS_B + (row - CONV_DIM - VALUE_DIM)] = acc;
        } else {
            ws[WS_A + (row - CONV_DIM - VALUE_DIM - NV)] = acc;
        }
    }
}

// ---------------- Kernel 2: recurrent state update ----------------
// One block per value head (32 blocks, 256 threads).
__global__ __launch_bounds__(256) void recur_kernel(
    const float* __restrict__ rec_state,  // 32x128x128
    float* __restrict__ ws,
    const float* __restrict__ dt_bias,    // 32
    const float* __restrict__ A_log,      // 32
    const float* __restrict__ norm_w,     // 128
    float* __restrict__ d_out)
{
    __shared__ float kk[DK], qq[DK], delta_s[DV];
    __shared__ float part[2][DV];
    __shared__ float red[8];

    const int h    = blockIdx.x;
    const int t    = threadIdx.x;
    const int lane = t & 63;
    const int wave = t >> 6;
    const int kh   = h >> 1;            // vpk = 2

    const float* conv_out = ws + WS_CONVOUT;

    // --- l2 norms of q,k (threads 0..127 hold one element each) ---
    float qv = 0.f, kv = 0.f;
    if (t < DK) {
        qv = conv_out[kh * DK + t];
        kv = conv_out[KEY_DIM + kh * DK + t];
    }
    float qs = wave_reduce_sum(qv * qv);
    float ks = wave_reduce_sum(kv * kv);
    if (lane == 0) { red[wave] = qs; red[4 + wave] = ks; }
    __syncthreads();
    float qscale = rsqrtf(red[0] + red[1] + 1e-6f) * 0.08838834764831845f; // * 1/sqrt(128)
    float kscale = rsqrtf(red[4] + red[5] + 1e-6f);
    if (t < DK) { qq[t] = qv * qscale; kk[t] = kv * kscale; }

    // --- gating scalars (computed redundantly by all threads) ---
    float bv = ws[WS_B + h];
    float av = ws[WS_A + h];
    float beta = 1.f / (1.f + expf(-bv));
    float spi = av + dt_bias[h];
    float sp  = (spi > 20.f) ? spi : log1pf(expf(spi));
    float gexp = expf(-expf(A_log[h]) * sp);
    __syncthreads();

    const int v    = t & 127;
    const int half = t >> 7;            // k range [half*64, half*64+64)
    const float* rec_h = rec_state + (size_t)h * DK * DV;

    // --- pass 1: kv_mem[v] = gexp * sum_k rec[k][v] * kk[k] ---
    float acc = 0.f;
    #pragma unroll 8
    for (int k = half * 64; k < half * 64 + 64; ++k)
        acc += rec_h[k * DV + v] * kk[k];
    part[half][v] = acc;
    __syncthreads();
    if (half == 0) {
        float kv_mem = (part[0][v] + part[1][v]) * gexp;
        float vval = conv_out[2 * KEY_DIM + h * DV + v];
        delta_s[v] = (vval - kv_mem) * beta;
    }
    __syncthreads();

    // --- pass 2: rec_new = gexp*rec + kk ⊗ delta; core[v] = rec_new · qq ---
    float dv  = delta_s[v];
    float core_acc = 0.f;
    float* rec_oh = d_out + OUT_REC + (size_t)h * DK * DV;
    #pragma unroll 4
    for (int k = half * 64; k < half * 64 + 64; ++k) {
        float rn = rec_h[k * DV + v] * gexp + kk[k] * dv;
        rec_oh[k * DV + v] = rn;
        core_acc += rn * qq[k];
    }
    part[half][v] = core_acc;
    __syncthreads();

    float core = 0.f;
    if (half == 0) core = part[0][v] + part[1][v];
    float c2 = wave_reduce_sum(core * core);      // waves 2,3 contribute 0
    if (lane == 0) red[wave] = c2;
    __syncthreads();
    float var = (red[0] + red[1]) * (1.f / 128.f);
    if (half == 0) {
        float zz = ws[WS_Z + h * DV + v];
        float xn = core * rsqrtf(var + 1e-6f) * norm_w[v];
        ws[WS_OUTVEC + h * DV + v] = xn * silu_f(zz);
    }
}

// ---------------- Kernel 3: out_proj GEMV (2048 x 4096) ----------------
__global__ __launch_bounds__(256) void outproj_kernel(
    const float* __restrict__ w,        // 2048x4096
    const float* __restrict__ ws,
    float* __restrict__ d_out)
{
    int row  = blockIdx.x * 4 + (threadIdx.x >> 6);
    int lane = threadIdx.x & 63;
    const float4* w4 = (const float4*)(w + (size_t)row * VALUE_DIM);
    const float4* x4 = (const float4*)(ws + WS_OUTVEC);
    float acc = 0.f;
    #pragma unroll
    for (int i = 0; i < VALUE_DIM / 4 / 64; ++i) {  // 16 iterations
        float4 a4 = w4[lane + i * 64];
        float4 b4 = x4[lane + i * 64];
        acc += a4.x * b4.x + a4.y * b4.y + a4.z * b4.z + a4.w * b4.w;
    }
    acc = wave_reduce_sum(acc);
    if (lane == 0) d_out[OUT_HIDDEN + row] = acc;
}

extern "C" void kernel_launch(void* const* d_in, const int* in_sizes, int n_in,
                              void* d_out, int out_size, void* d_ws, size_t ws_size,
                              hipStream_t stream) {
    const float* hidden_in  = (const float*)d_in[0];
    const float* conv_state = (const float*)d_in[1];
    const float* rec_state  = (const float*)d_in[2];
    const float* conv_w     = (const float*)d_in[3];
    const float* qkv_w      = (const float*)d_in[4];
    const float* z_w        = (const float*)d_in[5];
    const float* b_w        = (const float*)d_in[6];
    const float* a_w        = (const float*)d_in[7];
    const float* out_proj_w = (const float*)d_in[8];
    const float* dt_bias    = (const float*)d_in[9];
    const float* A_log      = (const float*)d_in[10];
    const float* norm_w     = (const float*)d_in[11];

    float* out = (float*)d_out;
    float* ws  = (float*)d_ws;

    proj_conv_kernel<<<N_PROJ_ROWS / 4, 256, 0, stream>>>(
        hidden_in, qkv_w, z_w, b_w, a_w, conv_state, conv_w, ws, out);
    recur_kernel<<<NV, 256, 0, stream>>>(
        rec_state, ws, dt_bias, A_log, norm_w, out);
    outproj_kernel<<<H / 4, 256, 0, stream>>>(out_proj_w, ws, out);
}

// Round 3
// 32.120 us; speedup vs baseline: 1.1442x; 1.1442x over previous
//
#include <hip/hip_runtime.h>
#include <math.h>

#define H 2048
#define NV 32
#define NK 16
#define DK 128
#define DV 128
#define KEY_DIM 2048
#define VALUE_DIM 4096
#define CONV_DIM 8192               // 2*KEY_DIM + VALUE_DIM
#define N_PROJ_ROWS (CONV_DIM + VALUE_DIM + NV + NV)   // 12352

// workspace float offsets
#define WS_CONVOUT 0                 // 8192
#define WS_ZSILU   8192              // 4096 (silu(z))
#define WS_B       12288             // 32
#define WS_A       12320             // 32
#define WS_Y       12352             // 4096 (core*norm_w*silu(z))
#define WS_VARP    16448             // 256  (per-block sum-of-squares partials)

// d_out float offsets
#define OUT_HIDDEN 0                 // 2048
#define OUT_CONV   2048              // 32768
#define OUT_REC    (2048 + 32768)    // 524288

__device__ __forceinline__ float wave_reduce_sum(float v) {
    #pragma unroll
    for (int off = 32; off > 0; off >>= 1)
        v += __shfl_down(v, off, 64);
    return v;
}

__device__ __forceinline__ float silu_f(float x) { return x / (1.f + expf(-x)); }

// ---------------- Kernel 1: fused projections + conv update ----------------
// One wave (64 lanes) per output row. Rows: [0,8192) qkv, [8192,12288) z,
// [12288,12320) b, [12320,12352) a.
__global__ __launch_bounds__(256) void proj_conv_kernel(
    const float* __restrict__ x,          // 2048
    const float* __restrict__ qkv_w,      // 8192x2048
    const float* __restrict__ z_w,        // 4096x2048
    const float* __restrict__ b_w,        // 32x2048
    const float* __restrict__ a_w,        // 32x2048
    const float* __restrict__ conv_state, // 8192x4
    const float* __restrict__ conv_w,     // 8192x4
    float* __restrict__ ws,
    float* __restrict__ d_out)
{
    int row  = blockIdx.x * 4 + (threadIdx.x >> 6);
    int lane = threadIdx.x & 63;
    if (row >= N_PROJ_ROWS) return;

    const float* w;
    if      (row < CONV_DIM)                  w = qkv_w + (size_t)row * H;
    else if (row < CONV_DIM + VALUE_DIM)      w = z_w   + (size_t)(row - CONV_DIM) * H;
    else if (row < CONV_DIM + VALUE_DIM + NV) w = b_w   + (size_t)(row - CONV_DIM - VALUE_DIM) * H;
    else                                      w = a_w   + (size_t)(row - CONV_DIM - VALUE_DIM - NV) * H;

    const float4* w4 = (const float4*)w;
    const float4* x4 = (const float4*)x;
    float acc = 0.f;
    #pragma unroll
    for (int i = 0; i < H / 4 / 64; ++i) {   // 8 iterations, 16B/lane each
        float4 a4 = w4[lane + i * 64];
        float4 b4 = x4[lane + i * 64];
        acc += a4.x * b4.x + a4.y * b4.y + a4.z * b4.z + a4.w * b4.w;
    }
    acc = wave_reduce_sum(acc);

    if (lane == 0) {
        if (row < CONV_DIM) {
            // conv epilogue: win = [cs1, cs2, cs3, mixed_qkv]
            float c1 = conv_state[row * 4 + 1];
            float c2 = conv_state[row * 4 + 2];
            float c3 = conv_state[row * 4 + 3];
            float w0 = conv_w[row * 4 + 0];
            float w1 = conv_w[row * 4 + 1];
            float w2 = conv_w[row * 4 + 2];
            float w3 = conv_w[row * 4 + 3];
            float s = c1 * w0 + c2 * w1 + c3 * w2 + acc * w3;
            ws[WS_CONVOUT + row] = silu_f(s);
            *(float4*)(d_out + OUT_CONV + row * 4) = make_float4(c1, c2, c3, acc);
        } else if (row < CONV_DIM + VALUE_DIM) {
            ws[WS_ZSILU + (row - CONV_DIM)] = silu_f(acc);
        } else if (row < CONV_DIM + VALUE_DIM + NV) {
            ws[WS_B + (row - CONV_DIM - VALUE_DIM)] = acc;
        } else {
            ws[WS_A + (row - CONV_DIM - VALUE_DIM - NV)] = acc;
        }
    }
}

// ---------------- Kernel 2: recurrent state update ----------------
// 256 blocks: 8 per value head, each owns 16 v-columns, full k range.
__global__ __launch_bounds__(256) void recur_kernel(
    const float* __restrict__ rec_state,  // 32x128x128
    float* __restrict__ ws,
    const float* __restrict__ dt_bias,    // 32
    const float* __restrict__ A_log,      // 32
    const float* __restrict__ norm_w,     // 128
    float* __restrict__ d_out)
{
    __shared__ float kk[DK], qq[DK];
    __shared__ float part[256];
    __shared__ float delta_s[16];
    __shared__ float red[8];

    const int b    = blockIdx.x;
    const int h    = b >> 3;            // head
    const int c    = b & 7;             // 16-column chunk within head
    const int t    = threadIdx.x;
    const int lane = t & 63;
    const int wave = t >> 6;
    const int kh   = h >> 1;            // vpk = 2

    const float* conv_out = ws + WS_CONVOUT;

    // --- l2 norms of q,k (threads 0..127 hold one element each) ---
    float qv = 0.f, kv = 0.f;
    if (t < DK) {
        qv = conv_out[kh * DK + t];
        kv = conv_out[KEY_DIM + kh * DK + t];
    }
    float qs = wave_reduce_sum(qv * qv);
    float ks = wave_reduce_sum(kv * kv);
    if (lane == 0) { red[wave] = qs; red[4 + wave] = ks; }
    __syncthreads();
    float qscale = rsqrtf(red[0] + red[1] + 1e-6f) * 0.08838834764831845f; // * 1/sqrt(128)
    float kscale = rsqrtf(red[4] + red[5] + 1e-6f);
    if (t < DK) { qq[t] = qv * qscale; kk[t] = kv * kscale; }

    // --- gating scalars (redundant per thread; cheap) ---
    float bv = ws[WS_B + h];
    float av = ws[WS_A + h];
    float beta = 1.f / (1.f + expf(-bv));
    float spi = av + dt_bias[h];
    float sp  = (spi > 20.f) ? spi : log1pf(expf(spi));
    float gexp = expf(-expf(A_log[h]) * sp);
    __syncthreads();

    const int v16 = t & 15;             // column within chunk
    const int kc  = t >> 4;             // 0..15, each covers 8 k
    const int v   = c * 16 + v16;       // global column in head
    const float* rec_h = rec_state + (size_t)h * DK * DV;

    // --- pass 1: partial kv_mem; keep rec values in registers ---
    float rv[8];
    float acc = 0.f;
    #pragma unroll
    for (int i = 0; i < 8; ++i) {
        int k = kc * 8 + i;
        rv[i] = rec_h[k * DV + v];
        acc += rv[i] * kk[k];
    }
    part[t] = acc;
    __syncthreads();
    if (t < 16) {
        float s = 0.f;
        #pragma unroll
        for (int j = 0; j < 16; ++j) s += part[j * 16 + t];
        float kv_mem = s * gexp;
        float vval = conv_out[2 * KEY_DIM + h * DV + c * 16 + t];
        delta_s[t] = (vval - kv_mem) * beta;
    }
    __syncthreads();

    // --- pass 2: rec_new = gexp*rec + kk ⊗ delta; core partial ---
    float dv = delta_s[v16];
    float core_acc = 0.f;
    float* rec_oh = d_out + OUT_REC + (size_t)h * DK * DV;
    #pragma unroll
    for (int i = 0; i < 8; ++i) {
        int k = kc * 8 + i;
        float rn = rv[i] * gexp + kk[k] * dv;
        rec_oh[k * DV + v] = rn;
        core_acc += rn * qq[k];
    }
    part[t] = core_acc;
    __syncthreads();
    if (t < 16) {
        float core = 0.f;
        #pragma unroll
        for (int j = 0; j < 16; ++j) core += part[j * 16 + t];
        int vg = c * 16 + t;
        float y = core * norm_w[vg] * ws[WS_ZSILU + h * DV + vg];
        ws[WS_Y + h * DV + vg] = y;
        float ss = core * core;         // lanes 0..15 of wave 0
        #pragma unroll
        for (int off = 8; off > 0; off >>= 1) ss += __shfl_down(ss, off, 64);
        if (t == 0) ws[WS_VARP + b] = ss;
    }
}

// ---------------- Kernel 3: norm finish + out_proj GEMV (2048 x 4096) ----------------
__global__ __launch_bounds__(256) void outproj_kernel(
    const float* __restrict__ w,        // 2048x4096
    const float* __restrict__ ws,
    float* __restrict__ d_out)
{
    __shared__ float xs[VALUE_DIM];     // 16 KB
    __shared__ float rstd[NV];
    const int t = threadIdx.x;

    if (t < NV) {
        float s = 0.f;
        #pragma unroll
        for (int j = 0; j < 8; ++j) s += ws[WS_VARP + t * 8 + j];
        rstd[t] = rsqrtf(s * (1.f / 128.f) + 1e-6f);
    }
    __syncthreads();
    #pragma unroll
    for (int i = 0; i < 4; ++i) {
        int idx = (t + i * 256) * 4;    // 0..4092, 128-aligned var groups
        float4 y = *(const float4*)(ws + WS_Y + idx);
        float r = rstd[idx >> 7];
        xs[idx + 0] = y.x * r; xs[idx + 1] = y.y * r;
        xs[idx + 2] = y.z * r; xs[idx + 3] = y.w * r;
    }
    __syncthreads();

    int row  = blockIdx.x * 4 + (t >> 6);
    int lane = t & 63;
    const float4* w4 = (const float4*)(w + (size_t)row * VALUE_DIM);
    float acc = 0.f;
    #pragma unroll
    for (int i = 0; i < VALUE_DIM / 4 / 64; ++i) {  // 16 iterations
        float4 a4 = w4[lane + i * 64];
        float4 b4 = *(const float4*)(xs + (lane + i * 64) * 4);
        acc += a4.x * b4.x + a4.y * b4.y + a4.z * b4.z + a4.w * b4.w;
    }
    acc = wave_reduce_sum(acc);
    if (lane == 0) d_out[OUT_HIDDEN + row] = acc;
}

extern "C" void kernel_launch(void* const* d_in, const int* in_sizes, int n_in,
                              void* d_out, int out_size, void* d_ws, size_t ws_size,
                              hipStream_t stream) {
    const float* hidden_in  = (const float*)d_in[0];
    const float* conv_state = (const float*)d_in[1];
    const float* rec_state  = (const float*)d_in[2];
    const float* conv_w     = (const float*)d_in[3];
    const float* qkv_w      = (const float*)d_in[4];
    const float* z_w        = (const float*)d_in[5];
    const float* b_w        = (const float*)d_in[6];
    const float* a_w        = (const float*)d_in[7];
    const float* out_proj_w = (const float*)d_in[8];
    const float* dt_bias    = (const float*)d_in[9];
    const float* A_log      = (const float*)d_in[10];
    const float* norm_w     = (const float*)d_in[11];

    float* out = (float*)d_out;
    float* ws  = (float*)d_ws;

    proj_conv_kernel<<<N_PROJ_ROWS / 4, 256, 0, stream>>>(
        hidden_in, qkv_w, z_w, b_w, a_w, conv_state, conv_w, ws, out);
    recur_kernel<<<NV * 8, 256, 0, stream>>>(
        rec_state, ws, dt_bias, A_log, norm_w, out);
    outproj_kernel<<<H / 4, 256, 0, stream>>>(out_proj_w, ws, out);
}

// Round 4
// 30.320 us; speedup vs baseline: 1.2121x; 1.0594x over previous
//
#include <hip/hip_runtime.h>
#include <math.h>

#define H 2048
#define NV 32
#define NK 16
#define DK 128
#define DV 128
#define KEY_DIM 2048
#define VALUE_DIM 4096
#define CONV_DIM 8192               // 2*KEY_DIM + VALUE_DIM

// workspace float offsets
#define WS_CONVOUT 0                 // 8192
#define WS_ZSILU   8192              // 4096 (silu(z))
#define WS_B       12288             // 32
#define WS_A       12320             // 32
#define WS_Y       12352             // 4096 (core*norm_w, pre-zsilu, pre-rstd)
#define WS_VARP    16448             // 128 (per-block sum-of-squares partials, 4/head)

// d_out float offsets
#define OUT_HIDDEN 0                 // 2048
#define OUT_CONV   2048              // 32768
#define OUT_REC    (2048 + 32768)    // 524288

__device__ __forceinline__ float wave_reduce_sum(float v) {
    #pragma unroll
    for (int off = 32; off > 0; off >>= 1)
        v += __shfl_down(v, off, 64);
    return v;
}

__device__ __forceinline__ float silu_f(float x) { return x / (1.f + expf(-x)); }

// ---------------- Kernel 1: qkv + b + a projections, conv update ----------------
// One wave per row. Rows: [0,8192) qkv, [8192,8224) b, [8224,8256) a.
__global__ __launch_bounds__(256) void proj_conv_kernel(
    const float* __restrict__ x,          // 2048
    const float* __restrict__ qkv_w,      // 8192x2048
    const float* __restrict__ b_w,        // 32x2048
    const float* __restrict__ a_w,        // 32x2048
    const float* __restrict__ conv_state, // 8192x4
    const float* __restrict__ conv_w,     // 8192x4
    float* __restrict__ ws,
    float* __restrict__ d_out)
{
    int row  = blockIdx.x * 4 + (threadIdx.x >> 6);
    int lane = threadIdx.x & 63;

    const float* w;
    if      (row < CONV_DIM)        w = qkv_w + (size_t)row * H;
    else if (row < CONV_DIM + NV)   w = b_w + (size_t)(row - CONV_DIM) * H;
    else                            w = a_w + (size_t)(row - CONV_DIM - NV) * H;

    const float4* w4 = (const float4*)w;
    const float4* x4 = (const float4*)x;
    float acc = 0.f;
    #pragma unroll
    for (int i = 0; i < H / 4 / 64; ++i) {   // 8 iterations, 16B/lane
        float4 a4 = w4[lane + i * 64];
        float4 b4 = x4[lane + i * 64];
        acc += a4.x * b4.x + a4.y * b4.y + a4.z * b4.z + a4.w * b4.w;
    }
    acc = wave_reduce_sum(acc);

    if (lane == 0) {
        if (row < CONV_DIM) {
            float c1 = conv_state[row * 4 + 1];
            float c2 = conv_state[row * 4 + 2];
            float c3 = conv_state[row * 4 + 3];
            float w0 = conv_w[row * 4 + 0];
            float w1 = conv_w[row * 4 + 1];
            float w2 = conv_w[row * 4 + 2];
            float w3 = conv_w[row * 4 + 3];
            float s = c1 * w0 + c2 * w1 + c3 * w2 + acc * w3;
            ws[WS_CONVOUT + row] = silu_f(s);
            *(float4*)(d_out + OUT_CONV + row * 4) = make_float4(c1, c2, c3, acc);
        } else if (row < CONV_DIM + NV) {
            ws[WS_B + (row - CONV_DIM)] = acc;
        } else {
            ws[WS_A + (row - CONV_DIM - NV)] = acc;
        }
    }
}

// ---------------- Kernel 2: recur (blocks 0..127) || z GEMV (blocks 128..1151) ----
// Recur: 4 blocks per head, each owns 32 contiguous v-columns; rec kept in regs
// between pass 1 and pass 2. z GEMV keeps HBM saturated while recur (latency-
// bound) runs concurrently.
__global__ __launch_bounds__(256) void mid_kernel(
    const float* __restrict__ x,          // 2048
    const float* __restrict__ z_w,        // 4096x2048
    const float* __restrict__ rec_state,  // 32x128x128
    float* __restrict__ ws,
    const float* __restrict__ dt_bias,    // 32
    const float* __restrict__ A_log,      // 32
    const float* __restrict__ norm_w,     // 128
    float* __restrict__ d_out)
{
    const int t = threadIdx.x;

    if (blockIdx.x >= 128) {
        // ---- z projection: one wave per row ----
        int row  = (blockIdx.x - 128) * 4 + (t >> 6);  // 0..4095
        int lane = t & 63;
        const float4* w4 = (const float4*)(z_w + (size_t)row * H);
        const float4* x4 = (const float4*)x;
        float acc = 0.f;
        #pragma unroll
        for (int i = 0; i < H / 4 / 64; ++i) {
            float4 a4 = w4[lane + i * 64];
            float4 b4 = x4[lane + i * 64];
            acc += a4.x * b4.x + a4.y * b4.y + a4.z * b4.z + a4.w * b4.w;
        }
        acc = wave_reduce_sum(acc);
        if (lane == 0) ws[WS_ZSILU + row] = silu_f(acc);
        return;
    }

    // ---- recurrent state update ----
    __shared__ float kk[DK], qq[DK];
    __shared__ float part[8][32];
    __shared__ float delta_s[32];
    __shared__ float red[8];

    const int b    = blockIdx.x;
    const int h    = b >> 2;            // head
    const int c    = b & 3;             // 32-column chunk
    const int lane = t & 63;
    const int wave = t >> 6;
    const int kh   = h >> 1;            // vpk = 2

    const float* conv_out = ws + WS_CONVOUT;

    float qv = 0.f, kv = 0.f;
    if (t < DK) {
        qv = conv_out[kh * DK + t];
        kv = conv_out[KEY_DIM + kh * DK + t];
    }
    float qs = wave_reduce_sum(qv * qv);
    float ks = wave_reduce_sum(kv * kv);
    if (lane == 0) { red[wave] = qs; red[4 + wave] = ks; }
    __syncthreads();
    float qscale = rsqrtf(red[0] + red[1] + 1e-6f) * 0.08838834764831845f; // * 1/sqrt(128)
    float kscale = rsqrtf(red[4] + red[5] + 1e-6f);
    if (t < DK) { qq[t] = qv * qscale; kk[t] = kv * kscale; }

    float bv = ws[WS_B + h];
    float av = ws[WS_A + h];
    float beta = 1.f / (1.f + expf(-bv));
    float spi = av + dt_bias[h];
    float sp  = (spi > 20.f) ? spi : log1pf(expf(spi));
    float gexp = expf(-expf(A_log[h]) * sp);
    __syncthreads();

    const int v32 = t & 31;
    const int kc  = t >> 5;             // 0..7, each covers 16 k
    const int v   = c * 32 + v32;
    const float* rec_h = rec_state + (size_t)h * DK * DV;

    // pass 1: partial kv_mem; rec values stay in registers
    float rv[16];
    float acc = 0.f;
    #pragma unroll
    for (int i = 0; i < 16; ++i) {
        int k = kc * 16 + i;
        rv[i] = rec_h[k * DV + v];
        acc += rv[i] * kk[k];
    }
    part[kc][v32] = acc;
    __syncthreads();
    if (t < 32) {
        float s = 0.f;
        #pragma unroll
        for (int j = 0; j < 8; ++j) s += part[j][t];
        float kv_mem = s * gexp;
        float vval = conv_out[2 * KEY_DIM + h * DV + c * 32 + t];
        delta_s[t] = (vval - kv_mem) * beta;
    }
    __syncthreads();

    // pass 2: rec_new = gexp*rec + kk ⊗ delta; core partial
    float dv = delta_s[v32];
    float core_acc = 0.f;
    float* rec_oh = d_out + OUT_REC + (size_t)h * DK * DV;
    #pragma unroll
    for (int i = 0; i < 16; ++i) {
        int k = kc * 16 + i;
        float rn = rv[i] * gexp + kk[k] * dv;
        rec_oh[k * DV + v] = rn;
        core_acc += rn * qq[k];
    }
    part[kc][v32] = core_acc;
    __syncthreads();
    if (t < 32) {
        float core = 0.f;
        #pragma unroll
        for (int j = 0; j < 8; ++j) core += part[j][t];
        int vg = c * 32 + t;
        ws[WS_Y + h * DV + vg] = core * norm_w[vg];
        float ss = core * core;         // lanes 0..31 of wave 0
        #pragma unroll
        for (int off = 16; off > 0; off >>= 1) ss += __shfl_down(ss, off, 32);
        if (t == 0) ws[WS_VARP + b] = ss;
    }
}

// ---------------- Kernel 3: norm+zsilu finish, out_proj GEMV (2048 x 4096) -----
__global__ __launch_bounds__(256) void outproj_kernel(
    const float* __restrict__ w,        // 2048x4096
    const float* __restrict__ ws,
    float* __restrict__ d_out)
{
    __shared__ float xs[VALUE_DIM];     // 16 KB
    __shared__ float rstd[NV];
    const int t = threadIdx.x;

    if (t < NV) {
        float s = ws[WS_VARP + t * 4 + 0] + ws[WS_VARP + t * 4 + 1]
                + ws[WS_VARP + t * 4 + 2] + ws[WS_VARP + t * 4 + 3];
        rstd[t] = rsqrtf(s * (1.f / 128.f) + 1e-6f);
    }
    __syncthreads();
    #pragma unroll
    for (int i = 0; i < 4; ++i) {
        int idx = (t + i * 256) * 4;    // 0..4092
        float4 y = *(const float4*)(ws + WS_Y + idx);
        float4 zs = *(const float4*)(ws + WS_ZSILU + idx);
        float r = rstd[idx >> 7];
        xs[idx + 0] = y.x * r * zs.x; xs[idx + 1] = y.y * r * zs.y;
        xs[idx + 2] = y.z * r * zs.z; xs[idx + 3] = y.w * r * zs.w;
    }
    __syncthreads();

    int row  = blockIdx.x * 4 + (t >> 6);
    int lane = t & 63;
    const float4* w4 = (const float4*)(w + (size_t)row * VALUE_DIM);
    float acc = 0.f;
    #pragma unroll
    for (int i = 0; i < VALUE_DIM / 4 / 64; ++i) {  // 16 iterations
        float4 a4 = w4[lane + i * 64];
        float4 b4 = *(const float4*)(xs + (lane + i * 64) * 4);
        acc += a4.x * b4.x + a4.y * b4.y + a4.z * b4.z + a4.w * b4.w;
    }
    acc = wave_reduce_sum(acc);
    if (lane == 0) d_out[OUT_HIDDEN + row] = acc;
}

extern "C" void kernel_launch(void* const* d_in, const int* in_sizes, int n_in,
                              void* d_out, int out_size, void* d_ws, size_t ws_size,
                              hipStream_t stream) {
    const float* hidden_in  = (const float*)d_in[0];
    const float* conv_state = (const float*)d_in[1];
    const float* rec_state  = (const float*)d_in[2];
    const float* conv_w     = (const float*)d_in[3];
    const float* qkv_w      = (const float*)d_in[4];
    const float* z_w        = (const float*)d_in[5];
    const float* b_w        = (const float*)d_in[6];
    const float* a_w        = (const float*)d_in[7];
    const float* out_proj_w = (const float*)d_in[8];
    const float* dt_bias    = (const float*)d_in[9];
    const float* A_log      = (const float*)d_in[10];
    const float* norm_w     = (const float*)d_in[11];

    float* out = (float*)d_out;
    float* ws  = (float*)d_ws;

    proj_conv_kernel<<<(CONV_DIM + 2 * NV) / 4, 256, 0, stream>>>(
        hidden_in, qkv_w, b_w, a_w, conv_state, conv_w, ws, out);
    mid_kernel<<<128 + VALUE_DIM / 4, 256, 0, stream>>>(
        hidden_in, z_w, rec_state, ws, dt_bias, A_log, norm_w, out);
    outproj_kernel<<<H / 4, 256, 0, stream>>>(out_proj_w, ws, out);
}